// Round 14
// baseline (241.909 us; speedup 1.0000x reference)
//
#include <hip/hip_runtime.h>
#include <stdint.h>

typedef __attribute__((ext_vector_type(4))) float  f32x4;
typedef __attribute__((ext_vector_type(8))) short  s16x8;
typedef __attribute__((ext_vector_type(4))) short  s16x4;
typedef __attribute__((ext_vector_type(4))) unsigned int u32x4;
typedef __attribute__((ext_vector_type(2))) unsigned int u32x2;

__device__ __forceinline__ unsigned short f2bf(float x) {
  union { float f; unsigned int u; } a; a.f = x;
  unsigned int lsb = (a.u >> 16) & 1u;
  a.u += 0x7fffu + lsb;                    // round-to-nearest-even
  return (unsigned short)(a.u >> 16);
}
__device__ __forceinline__ float bf2f(unsigned short h) {
  union { unsigned int u; float f; } a; a.u = ((unsigned int)h) << 16; return a.f;
}
// HW packed f32->bf16 RNE: lo16 = bf16(a), hi16 = bf16(b). Bit-identical to f2bf.
__device__ __forceinline__ unsigned int cvtpk(float a, float b) {
  unsigned int d;
  asm("v_cvt_pk_bf16_f32 %0, %1, %2" : "=v"(d) : "v"(a), "v"(b));
  return d;
}
__device__ __forceinline__ float bflo_f(unsigned int u) {
  union { unsigned int u; float f; } x; x.u = u << 16; return x.f;
}
__device__ __forceinline__ float bfhi_f(unsigned int u) {
  union { unsigned int u; float f; } x; x.u = u & 0xffff0000u; return x.f;
}
__device__ __forceinline__ s16x8 pk4(unsigned a, unsigned b, unsigned c, unsigned d) {
  union { u32x4 u; s16x8 s; } x;
  u32x4 v = {a, b, c, d}; x.u = v; return x.s;
}

__device__ __forceinline__ void gload_lds16(const void* g, void* s) {
  __builtin_amdgcn_global_load_lds(
      (__attribute__((address_space(1))) void*)g,
      (__attribute__((address_space(3))) void*)s, 16, 0, 0);
}

#define VMCNT(N) asm volatile("s_waitcnt vmcnt(" #N ")" ::: "memory")
#define LGKM0()  asm volatile("s_waitcnt lgkmcnt(0)" ::: "memory")
#define SBAR()   __builtin_amdgcn_s_barrier()
#define SFENCE() __builtin_amdgcn_sched_barrier(0)

// ---------------- K2: f32 -> bf16 (hi only) ----------------
__global__ __launch_bounds__(256) void k_convert_hi(
    const float* __restrict__ in, unsigned short* __restrict__ out, int n4) {
  int i = blockIdx.x * 256 + threadIdx.x;
  if (i < n4) {
    f32x4 v = ((const f32x4*)in)[i];
    u32x2 h;
    h[0] = cvtpk(v[0], v[1]);
    h[1] = cvtpk(v[2], v[3]);
    ((u32x2*)out)[i] = h;
  }
}

// ---------------- K3: f32 TN gemm: C[m][n] = sum_k A[m][k]*B[n][k] + bias[n] ----------------
__global__ __launch_bounds__(256) void k_gemm_f32_tn(
    const float* __restrict__ A, const float* __restrict__ Bm,
    const float* __restrict__ bias, float* __restrict__ C,
    int M, int N, int K) {
  __shared__ float As[32][33], Bs[32][33];
  int tid = threadIdx.x;
  int bm = blockIdx.x * 32, bn = blockIdx.y * 32;
  int tr = tid & 31, tq = tid >> 5;
  float acc[4] = {0.f, 0.f, 0.f, 0.f};
  for (int k0 = 0; k0 < K; k0 += 32) {
#pragma unroll
    for (int i = 0; i < 4; i++) {
      int idx = tid + i * 256;
      int r = idx >> 5, c = idx & 31;
      As[r][c] = A[(size_t)(bm + r) * K + k0 + c];
      Bs[r][c] = Bm[(size_t)(bn + r) * K + k0 + c];
    }
    __syncthreads();
#pragma unroll
    for (int kk = 0; kk < 32; kk++) {
      float b = Bs[tr][kk];
#pragma unroll
      for (int i = 0; i < 4; i++) acc[i] += As[tq * 4 + i][kk] * b;
    }
    __syncthreads();
  }
#pragma unroll
  for (int i = 0; i < 4; i++)
    C[(size_t)(bm + tq * 4 + i) * N + bn + tr] = acc[i] + bias[bn + tr];
}

// ---------------- K4: f32 NN gemm + bf16 hi/lo split output ----------------
__global__ __launch_bounds__(256) void k_gemm_f32_nn_split(
    const float* __restrict__ A, const float* __restrict__ Bm,
    unsigned short* __restrict__ Chi, unsigned short* __restrict__ Clo,
    int M, int N, int K) {
  __shared__ float As[32][33], Bs[32][33];
  int tid = threadIdx.x;
  int bm = blockIdx.x * 32, bn = blockIdx.y * 32;
  int tr = tid & 31, tq = tid >> 5;
  float acc[4] = {0.f, 0.f, 0.f, 0.f};
  for (int k0 = 0; k0 < K; k0 += 32) {
#pragma unroll
    for (int i = 0; i < 4; i++) {
      int idx = tid + i * 256;
      int r = idx >> 5, c = idx & 31;
      As[r][c] = A[(size_t)(bm + r) * K + k0 + c];
      Bs[r][c] = Bm[(size_t)(k0 + r) * N + bn + c];
    }
    __syncthreads();
#pragma unroll
    for (int kk = 0; kk < 32; kk++) {
      float b = Bs[kk][tr];
#pragma unroll
      for (int i = 0; i < 4; i++) acc[i] += As[tq * 4 + i][kk] * b;
    }
    __syncthreads();
  }
#pragma unroll
  for (int i = 0; i < 4; i++) {
    float q = acc[i];
    unsigned short hb = f2bf(q);
    size_t o = (size_t)(bm + tq * 4 + i) * N + bn + tr;
    Chi[o] = hb;
    Clo[o] = f2bf(q - bf2f(hb));
  }
}

// ---------------- K5: fused scores + softmax + ctx ----------------
// Block (b, lq): scores S[32 l][256 r] = QW[lq] @ img[b]^T, then softmax,
// then ctx[b][lq*32..][*] = P @ img[b]. 512 threads = 8 waves (1x8).
// LDS ~74 KB -> 2 blocks/CU; grid 512 -> cross-block latency hiding.
__global__ __launch_bounds__(512, 2) void k_fused(
    const unsigned short* __restrict__ QWh, const unsigned short* __restrict__ QWl,
    const float* __restrict__ img, unsigned short* __restrict__ Cp) {
  // scores bufs @0, @36864 (each: Ah@0 2K, Al@2048 2K, Bh@4096 16K, Bl@20480 16K)
  // after scores: P@0 (16K), ctx bufs @16384/@32768/@49152 (16K each),
  // RMAX@73728 (1K: 73728..74751), RSUM@74752 (1K: 74752..75775).
  __shared__ __attribute__((aligned(16))) char lds[75776];
  int tid = threadIdx.x, l = tid & 63, w = tid >> 6;   // 8 waves, grid 1x8
  int lr = l & 15, lk8 = l >> 4;
  int sF = (lr >> 1) & 3;
  int rh = lk8 * 4;
  int bid = blockIdx.x;
  int xcd = bid & 7, loc = bid >> 3;        // loc 0..63
  int b = xcd * 16 + (loc >> 2);            // 4 lq-blocks of b share one XCD
  int lq = loc & 3;
  const int BUFSZ = 36864;
  const int RMAX = 73728, RSUM = 74752;

  // ---- scores A staging (QW hi/lo, 32 rows): waves 0-1 hi, 2-3 lo ----
  int t2 = tid & 127;
  int arow = t2 >> 2, achk = (t2 & 3) ^ ((t2 >> 3) & 3);
  const unsigned short* aW = (w & 2) ? QWl : QWh;
  const unsigned short* asrc = aW + (size_t)(lq * 32 + arow) * 1024 + achk * 8;
  int aDst = ((w & 2) ? 2048 : 0) + (w & 1) * 1024;
  // ---- scores B staging (reg): row tid>>1 (0..255), 16 k as 2 chunks ----
  int brow = tid >> 1;
  int c0 = 2 * (tid & 1), c1 = c0 + 1, sw = (brow >> 1) & 3;
  const float* gBr = img + ((size_t)b * 256 + brow) * 1024 + (tid & 1) * 16;
  int bByte0 = brow * 64 + ((c0 ^ sw) << 4);
  int bByte1 = brow * 64 + ((c1 ^ sw) << 4);

  f32x4 v0, v1, v2, v3;
  f32x4 acc[2][2] = {};

#define SC_LOADB(K0) { \
    v0 = *(const f32x4*)(gBr + (K0)); \
    v1 = *(const f32x4*)(gBr + (K0) + 4); \
    v2 = *(const f32x4*)(gBr + (K0) + 8); \
    v3 = *(const f32x4*)(gBr + (K0) + 12); }

#define SC_CONV(DST) { \
    unsigned h0 = cvtpk(v0[0], v0[1]), h1 = cvtpk(v0[2], v0[3]); \
    unsigned h2 = cvtpk(v1[0], v1[1]), h3 = cvtpk(v1[2], v1[3]); \
    unsigned g0 = cvtpk(v2[0], v2[1]), g1 = cvtpk(v2[2], v2[3]); \
    unsigned g2 = cvtpk(v3[0], v3[1]), g3 = cvtpk(v3[2], v3[3]); \
    unsigned q0 = cvtpk(v0[0] - bflo_f(h0), v0[1] - bfhi_f(h0)); \
    unsigned q1 = cvtpk(v0[2] - bflo_f(h1), v0[3] - bfhi_f(h1)); \
    unsigned q2 = cvtpk(v1[0] - bflo_f(h2), v1[1] - bfhi_f(h2)); \
    unsigned q3 = cvtpk(v1[2] - bflo_f(h3), v1[3] - bfhi_f(h3)); \
    unsigned r0 = cvtpk(v2[0] - bflo_f(g0), v2[1] - bfhi_f(g0)); \
    unsigned r1 = cvtpk(v2[2] - bflo_f(g1), v2[3] - bfhi_f(g1)); \
    unsigned r2 = cvtpk(v3[0] - bflo_f(g2), v3[1] - bfhi_f(g2)); \
    unsigned r3 = cvtpk(v3[2] - bflo_f(g3), v3[3] - bfhi_f(g3)); \
    *(s16x8*)((DST) + 4096 + bByte0) = pk4(h0, h1, h2, h3); \
    *(s16x8*)((DST) + 4096 + bByte1) = pk4(g0, g1, g2, g3); \
    *(s16x8*)((DST) + 20480 + bByte0) = pk4(q0, q1, q2, q3); \
    *(s16x8*)((DST) + 20480 + bByte1) = pk4(r0, r1, r2, r3); }

#define SC_COMPUTE(BUF) { \
    s16x8 ah[2], al2[2], bh[2], bl[2]; \
    _Pragma("unroll") \
    for (int i = 0; i < 2; i++) { \
      int row = i * 16 + lr; \
      int byte = row * 64 + ((lk8 ^ sF) << 4); \
      ah[i] = *(const s16x8*)((BUF) + byte); \
      al2[i] = *(const s16x8*)((BUF) + 2048 + byte); \
    } \
    _Pragma("unroll") \
    for (int j = 0; j < 2; j++) { \
      int n = w * 32 + j * 16 + lr; \
      int byte = n * 64 + ((lk8 ^ sF) << 4); \
      bh[j] = *(const s16x8*)((BUF) + 4096 + byte); \
      bl[j] = *(const s16x8*)((BUF) + 20480 + byte); \
    } \
    __builtin_amdgcn_s_setprio(1); \
    _Pragma("unroll") \
    for (int i = 0; i < 2; i++) \
      _Pragma("unroll") \
      for (int j = 0; j < 2; j++) { \
        acc[i][j] = __builtin_amdgcn_mfma_f32_16x16x32_bf16(ah[i], bh[j], acc[i][j], 0, 0, 0); \
        acc[i][j] = __builtin_amdgcn_mfma_f32_16x16x32_bf16(ah[i], bl[j], acc[i][j], 0, 0, 0); \
        acc[i][j] = __builtin_amdgcn_mfma_f32_16x16x32_bf16(al2[i], bh[j], acc[i][j], 0, 0, 0); \
      } \
    __builtin_amdgcn_s_setprio(0); }

  // prologue: tile 0 into buf0
  SC_LOADB(0);
  SFENCE();
  if (w < 4) gload_lds16(asrc, lds + aDst);
  SFENCE();
  SC_CONV(lds);
  VMCNT(0);
  LGKM0();
  SBAR();
  SFENCE();
#pragma unroll 1
  for (int t = 0; t < 32; ++t) {
    char* cur = lds + (t & 1) * BUFSZ;
    char* nxt = lds + ((t + 1) & 1) * BUFSZ;
    if (t < 31) {
      SC_LOADB((t + 1) * 32);
      SFENCE();
      if (w < 4) gload_lds16(asrc + (t + 1) * 32, nxt + aDst);
      SFENCE();
    }
    SC_COMPUTE(cur);
    if (t < 31) SC_CONV(nxt);
    VMCNT(0);
    LGKM0();
    SBAR();
    SFENCE();
  }
#undef SC_COMPUTE
#undef SC_CONV
#undef SC_LOADB

  // ---- softmax over r=256 (32 rows), in-register + LDS reduce (8 partials) ----
  {
#pragma unroll
    for (int i = 0; i < 2; i++)
#pragma unroll
      for (int q = 0; q < 4; q++) {
        float m = fmaxf(acc[i][0][q], acc[i][1][q]);
#pragma unroll
        for (int s = 1; s < 16; s <<= 1) m = fmaxf(m, __shfl_xor(m, s, 64));
        if (lr == 0)
          *(float*)(lds + RMAX + (i * 16 + rh + q) * 32 + w * 4) = m;
      }
    LGKM0();
    SBAR();
#pragma unroll
    for (int i = 0; i < 2; i++)
#pragma unroll
      for (int q = 0; q < 4; q++) {
        int row = i * 16 + rh + q;
        const float* rm = (const float*)(lds + RMAX + row * 32);
        float g = fmaxf(fmaxf(fmaxf(rm[0], rm[1]), fmaxf(rm[2], rm[3])),
                        fmaxf(fmaxf(rm[4], rm[5]), fmaxf(rm[6], rm[7])));
        float ps = 0.f;
#pragma unroll
        for (int j = 0; j < 2; j++) {
          float e0 = __expf(acc[i][j][q] - g);
          acc[i][j][q] = e0;
          ps += e0;
        }
#pragma unroll
        for (int s = 1; s < 16; s <<= 1) ps += __shfl_xor(ps, s, 64);
        if (lr == 0) *(float*)(lds + RSUM + row * 32 + w * 4) = ps;
      }
    LGKM0();
    SBAR();
    // P write: all scores-buf reads complete (barrier above)
#pragma unroll
    for (int i = 0; i < 2; i++)
#pragma unroll
      for (int q = 0; q < 4; q++) {
        int row = i * 16 + rh + q;
        const float* rs = (const float*)(lds + RSUM + row * 32);
        float sum = (rs[0] + rs[1]) + (rs[2] + rs[3]);
        sum += (rs[4] + rs[5]) + (rs[6] + rs[7]);
        float sc = 0.03125f / sum;
#pragma unroll
        for (int j = 0; j < 2; j++) {
          int col = w * 32 + j * 16 + lr;
          int byte = row * 512 +
                     (((col >> 3) ^ ((row & 7) << 2)) << 4) + (col & 7) * 2;
          *(unsigned short*)(lds + byte) = f2bf(acc[i][j][q] * sc);
        }
      }
    LGKM0();
    SBAR();
    SFENCE();
  }

  // ---- ctx: ctx[32 l][1024 d] = P @ img[b], 32 steps (4 d-chunks x 8 k) ----
  {
    int u = tid & 15, dc = tid >> 4;        // u: r-pair, dc: 8-d group (0..31)
    const float* gva = img + ((size_t)b * 256 + 2 * u) * 1024 + dc * 8;
    const float* gvb = gva + 1024;
    char* ccur = lds + 16384;
    char* cnxt = lds + 32768;
    char* cnx2 = lds + 49152;
    f32x4 vAa, vAb, vAc, vAd, vBa, vBb, vBc, vBd;
    f32x4 acc2[2][2] = {};

#define CTX_LOAD(T, Ra, Rb, Rc, Rd) { \
    int tt = ((T) < 32) ? (T) : 31; \
    size_t off = (size_t)((tt & 7) * 32) * 1024 + (tt >> 3) * 256; \
    Ra = *(const f32x4*)(gva + off); \
    Rb = *(const f32x4*)(gva + off + 4); \
    Rc = *(const f32x4*)(gvb + off); \
    Rd = *(const f32x4*)(gvb + off + 4); }

#define CTX_CONV(DST, Ra, Rb, Rc, Rd) { \
    _Pragma("unroll") \
    for (int j = 0; j < 8; j++) { \
      float x0 = (j < 4) ? (Ra)[j & 3] : (Rb)[j & 3]; \
      float x1 = (j < 4) ? (Rc)[j & 3] : (Rd)[j & 3]; \
      int dd = dc * 8 + j; \
      unsigned int w32 = cvtpk(x0, x1); \
      int byte = dd * 64 + ((4 * u) ^ (((dd >> 1) & 3) << 4)); \
      *(unsigned int*)((DST) + byte) = w32; \
    } }

#define CTX_STEP(T, CIa, CIb, CIc, CId, COa, COb, COc, COd) { \
    CTX_LOAD((T) + 2, COa, COb, COc, COd); \
    SFENCE(); \
    s16x8 af[2], bf[2]; \
    _Pragma("unroll") \
    for (int i = 0; i < 2; i++) { \
      int row = i * 16 + lr; \
      int rc = ((T) & 7) * 4 + lk8; \
      int byte = row * 512 + ((rc ^ ((row & 7) << 2)) << 4); \
      af[i] = *(const s16x8*)(lds + byte); \
    } \
    _Pragma("unroll") \
    for (int j = 0; j < 2; j++) { \
      int n = w * 32 + j * 16 + lr; \
      int byte = n * 64 + ((lk8 ^ ((n >> 1) & 3)) << 4); \
      bf[j] = *(const s16x8*)(ccur + byte); \
    } \
    __builtin_amdgcn_s_setprio(1); \
    _Pragma("unroll") \
    for (int i = 0; i < 2; i++) \
      _Pragma("unroll") \
      for (int j = 0; j < 2; j++) \
        acc2[i][j] = __builtin_amdgcn_mfma_f32_16x16x32_bf16(af[i], bf[j], acc2[i][j], 0, 0, 0); \
    __builtin_amdgcn_s_setprio(0); \
    CTX_CONV(cnxt, CIa, CIb, CIc, CId); \
    if (((T) & 7) == 7) { \
      int d0c = ((T) >> 3) * 256; \
      _Pragma("unroll") \
      for (int i = 0; i < 2; i++) \
        _Pragma("unroll") \
        for (int q = 0; q < 4; q++) { \
          int gl = lq * 32 + i * 16 + rh + q; \
          _Pragma("unroll") \
          for (int j = 0; j < 2; j++) { \
            int gn = d0c + w * 32 + j * 16 + lr; \
            Cp[((size_t)b * 128 + gl) * 1024 + gn] = f2bf(acc2[i][j][q]); \
            acc2[i][j][q] = 0.f; \
          } \
        } \
    } \
    VMCNT(4); \
    LGKM0(); \
    SBAR(); \
    SFENCE(); \
    { char* t_ = ccur; ccur = cnxt; cnxt = cnx2; cnx2 = t_; } }

    CTX_LOAD(0, vAa, vAb, vAc, vAd);
    SFENCE();
    CTX_LOAD(1, vBa, vBb, vBc, vBd);
    SFENCE();
    CTX_CONV(ccur, vAa, vAb, vAc, vAd);
    VMCNT(4);
    LGKM0();
    SBAR();
    SFENCE();
#pragma unroll 1
    for (int it = 0; it < 16; ++it) {
      int t0 = 2 * it;
      CTX_STEP(t0,     vBa, vBb, vBc, vBd, vAa, vAb, vAc, vAd);
      CTX_STEP(t0 + 1, vAa, vAb, vAc, vAd, vBa, vBb, vBc, vBd);
    }
#undef CTX_STEP
#undef CTX_CONV
#undef CTX_LOAD
  }
}

// ---------------- K10: out[m][n] = sum_k ctx[m][k]*Wv[n][k] + bv[n]/32 ----------------
// 256x128 tile, 512 threads (8 waves 4x2), 3-buf counted vmcnt(3).
__global__ __launch_bounds__(512, 2) void k_gemm_out(
    const unsigned short* __restrict__ A, const unsigned short* __restrict__ Bm,
    const float* __restrict__ bv, float* __restrict__ Out) {
  __shared__ __attribute__((aligned(16))) char lds[73728];
  int tid = threadIdx.x, l = tid & 63, w = tid >> 6;   // 8 waves
  int wm = w >> 1, wn = w & 1;                          // 4 x 2
  int rid = blockIdx.x;
  int xcd = rid & 7, lid = rid >> 3;
  int bm = (xcd * 8 + (lid >> 3)) * 256;
  int bn = (lid & 7) * 128;
  int lr = l & 15, lk8 = l >> 4;
  int sF = (lr >> 1) & 3;
  int srow = tid >> 2;                      // 0..127
  int swz = (tid & 3) ^ ((tid >> 3) & 3);
  const unsigned short* a0 = A + (size_t)(bm + srow) * 1024 + swz * 8;
  const unsigned short* a1 = A + (size_t)(bm + 128 + srow) * 1024 + swz * 8;
  const unsigned short* b0 = Bm + (size_t)(bn + srow) * 1024 + swz * 8;
  char* cur = &lds[0];
  char* nxt = &lds[24576];
  char* nx2 = &lds[49152];
  f32x4 acc[4][4] = {};

#define OUT_STAGE(KN, BUF) { \
    gload_lds16(a0 + (KN), (BUF) + w * 1024); \
    gload_lds16(a1 + (KN), (BUF) + 8192 + w * 1024); \
    gload_lds16(b0 + (KN), (BUF) + 16384 + w * 1024); }

#define OUT_STEP(T) { \
    int kn = (((T) + 2 < 32) ? (T) + 2 : 31) * 32; \
    OUT_STAGE(kn, nx2); \
    SFENCE(); \
    s16x8 af[4], bf[4]; \
    _Pragma("unroll") \
    for (int i = 0; i < 4; i++) { \
      int byte = (wm * 64 + i * 16 + lr) * 64 + ((lk8 ^ sF) << 4); \
      af[i] = *(const s16x8*)(cur + byte); \
    } \
    _Pragma("unroll") \
    for (int i = 0; i < 4; i++) { \
      int byte = 16384 + (wn * 64 + i * 16 + lr) * 64 + ((lk8 ^ sF) << 4); \
      bf[i] = *(const s16x8*)(cur + byte); \
    } \
    __builtin_amdgcn_s_setprio(1); \
    _Pragma("unroll") \
    for (int i = 0; i < 4; i++) \
      _Pragma("unroll") \
      for (int j = 0; j < 4; j++) \
        acc[i][j] = __builtin_amdgcn_mfma_f32_16x16x32_bf16(af[i], bf[j], acc[i][j], 0, 0, 0); \
    __builtin_amdgcn_s_setprio(0); \
    VMCNT(3); \
    SBAR(); \
    SFENCE(); \
    { char* t_ = cur; cur = nxt; nxt = nx2; nx2 = t_; } }

  OUT_STAGE(0, cur);
  SFENCE();
  OUT_STAGE(32, nxt);
  SFENCE();
  VMCNT(3);
  SBAR();
  SFENCE();

#pragma unroll 1
  for (int t = 0; t < 32; ++t) {
    OUT_STEP(t);
  }

  int rh = (l >> 4) * 4;
#pragma unroll
  for (int i = 0; i < 4; i++)
#pragma unroll
    for (int q = 0; q < 4; q++) {
      int gm = bm + wm * 64 + i * 16 + rh + q;
#pragma unroll
      for (int j = 0; j < 4; j++) {
        int gn = bn + wn * 64 + j * 16 + lr;
        Out[(size_t)gm * 1024 + gn] = acc[i][j][q] + 0.03125f * bv[gn];
      }
    }
#undef OUT_STEP
#undef OUT_STAGE
}

extern "C" void kernel_launch(void* const* d_in, const int* in_sizes, int n_in,
                              void* d_out, int out_size, void* d_ws, size_t ws_size,
                              hipStream_t stream) {
  const float* cap = (const float*)d_in[0];
  const float* img = (const float*)d_in[1];
  const float* Wq  = (const float*)d_in[2];
  const float* bq  = (const float*)d_in[3];
  const float* Wk  = (const float*)d_in[4];
  // d_in[5] = bk: constant across r -> cancels in softmax. Unused.
  const float* Wv  = (const float*)d_in[6];
  const float* bv  = (const float*)d_in[7];
  float* out = (float*)d_out;

  char* ws = (char*)d_ws;
  if (ws_size < 36700160ull) return;  // fail loudly (output stays poisoned)
  unsigned short* ctx = (unsigned short*)(ws);               // 32 MB
  float*          Qb  = (float*)(ws + 33554432);             // 512 KB
  unsigned short* QWh = (unsigned short*)(ws + 34078720);    // 256 KB
  unsigned short* QWl = (unsigned short*)(ws + 34340864);    // 256 KB
  unsigned short* Wvh = (unsigned short*)(ws + 34603008);    //   2 MB

  k_convert_hi<<<1024, 256, 0, stream>>>(Wv, Wvh, 1048576 / 4);
  // Q = cap @ Wq^T + bq  (f32)
  k_gemm_f32_tn<<<dim3(4, 32), 256, 0, stream>>>(cap, Wq, bq, Qb, 128, 1024, 1024);
  // QW = Q @ Wk  (f32 -> bf16 hi/lo)
  k_gemm_f32_nn_split<<<dim3(4, 32), 256, 0, stream>>>(Qb, Wk, QWh, QWl, 128, 1024, 1024);
  // fused: scores (3-pass split bf16) + softmax/32 + ctx, 2 blocks/CU
  k_fused<<<512, 512, 0, stream>>>(QWh, QWl, img, ctx);
  // out = ctx @ Wv^T + bv/32  (256x128 counted-vmcnt pipeline)
  k_gemm_out<<<512, 512, 0, stream>>>(ctx, Wvh, bv, out);
}

// Round 15
// 210.689 us; speedup vs baseline: 1.1482x; 1.1482x over previous
//
#include <hip/hip_runtime.h>
#include <stdint.h>

typedef __attribute__((ext_vector_type(4))) float  f32x4;
typedef __attribute__((ext_vector_type(8))) short  s16x8;
typedef __attribute__((ext_vector_type(4))) short  s16x4;
typedef __attribute__((ext_vector_type(4))) unsigned int u32x4;
typedef __attribute__((ext_vector_type(2))) unsigned int u32x2;

__device__ __forceinline__ unsigned short f2bf(float x) {
  union { float f; unsigned int u; } a; a.f = x;
  unsigned int lsb = (a.u >> 16) & 1u;
  a.u += 0x7fffu + lsb;                    // round-to-nearest-even
  return (unsigned short)(a.u >> 16);
}
__device__ __forceinline__ float bf2f(unsigned short h) {
  union { unsigned int u; float f; } a; a.u = ((unsigned int)h) << 16; return a.f;
}
// HW packed f32->bf16 RNE: lo16 = bf16(a), hi16 = bf16(b). Bit-identical to f2bf.
__device__ __forceinline__ unsigned int cvtpk(float a, float b) {
  unsigned int d;
  asm("v_cvt_pk_bf16_f32 %0, %1, %2" : "=v"(d) : "v"(a), "v"(b));
  return d;
}
__device__ __forceinline__ float bflo_f(unsigned int u) {
  union { unsigned int u; float f; } x; x.u = u << 16; return x.f;
}
__device__ __forceinline__ float bfhi_f(unsigned int u) {
  union { unsigned int u; float f; } x; x.u = u & 0xffff0000u; return x.f;
}
__device__ __forceinline__ s16x8 pk4(unsigned a, unsigned b, unsigned c, unsigned d) {
  union { u32x4 u; s16x8 s; } x;
  u32x4 v = {a, b, c, d}; x.u = v; return x.s;
}

__device__ __forceinline__ void gload_lds16(const void* g, void* s) {
  __builtin_amdgcn_global_load_lds(
      (__attribute__((address_space(1))) void*)g,
      (__attribute__((address_space(3))) void*)s, 16, 0, 0);
}

#define VMCNT(N) asm volatile("s_waitcnt vmcnt(" #N ")" ::: "memory")
#define LGKM0()  asm volatile("s_waitcnt lgkmcnt(0)" ::: "memory")
#define SBAR()   __builtin_amdgcn_s_barrier()
#define SFENCE() __builtin_amdgcn_sched_barrier(0)

// ---------------- K2: f32 -> bf16 (hi only) ----------------
__global__ __launch_bounds__(256) void k_convert_hi(
    const float* __restrict__ in, unsigned short* __restrict__ out, int n4) {
  int i = blockIdx.x * 256 + threadIdx.x;
  if (i < n4) {
    f32x4 v = ((const f32x4*)in)[i];
    u32x2 h;
    h[0] = cvtpk(v[0], v[1]);
    h[1] = cvtpk(v[2], v[3]);
    ((u32x2*)out)[i] = h;
  }
}

// ---------------- K3: f32 TN gemm: C[m][n] = sum_k A[m][k]*B[n][k] + bias[n] ----------------
__global__ __launch_bounds__(256) void k_gemm_f32_tn(
    const float* __restrict__ A, const float* __restrict__ Bm,
    const float* __restrict__ bias, float* __restrict__ C,
    int M, int N, int K) {
  __shared__ float As[32][33], Bs[32][33];
  int tid = threadIdx.x;
  int bm = blockIdx.x * 32, bn = blockIdx.y * 32;
  int tr = tid & 31, tq = tid >> 5;
  float acc[4] = {0.f, 0.f, 0.f, 0.f};
  for (int k0 = 0; k0 < K; k0 += 32) {
#pragma unroll
    for (int i = 0; i < 4; i++) {
      int idx = tid + i * 256;
      int r = idx >> 5, c = idx & 31;
      As[r][c] = A[(size_t)(bm + r) * K + k0 + c];
      Bs[r][c] = Bm[(size_t)(bn + r) * K + k0 + c];
    }
    __syncthreads();
#pragma unroll
    for (int kk = 0; kk < 32; kk++) {
      float b = Bs[tr][kk];
#pragma unroll
      for (int i = 0; i < 4; i++) acc[i] += As[tq * 4 + i][kk] * b;
    }
    __syncthreads();
  }
#pragma unroll
  for (int i = 0; i < 4; i++)
    C[(size_t)(bm + tq * 4 + i) * N + bn + tr] = acc[i] + bias[bn + tr];
}

// ---------------- K4: f32 NN gemm + bf16 hi/lo split output ----------------
__global__ __launch_bounds__(256) void k_gemm_f32_nn_split(
    const float* __restrict__ A, const float* __restrict__ Bm,
    unsigned short* __restrict__ Chi, unsigned short* __restrict__ Clo,
    int M, int N, int K) {
  __shared__ float As[32][33], Bs[32][33];
  int tid = threadIdx.x;
  int bm = blockIdx.x * 32, bn = blockIdx.y * 32;
  int tr = tid & 31, tq = tid >> 5;
  float acc[4] = {0.f, 0.f, 0.f, 0.f};
  for (int k0 = 0; k0 < K; k0 += 32) {
#pragma unroll
    for (int i = 0; i < 4; i++) {
      int idx = tid + i * 256;
      int r = idx >> 5, c = idx & 31;
      As[r][c] = A[(size_t)(bm + r) * K + k0 + c];
      Bs[r][c] = Bm[(size_t)(k0 + r) * N + bn + c];
    }
    __syncthreads();
#pragma unroll
    for (int kk = 0; kk < 32; kk++) {
      float b = Bs[kk][tr];
#pragma unroll
      for (int i = 0; i < 4; i++) acc[i] += As[tq * 4 + i][kk] * b;
    }
    __syncthreads();
  }
#pragma unroll
  for (int i = 0; i < 4; i++) {
    float q = acc[i];
    unsigned short hb = f2bf(q);
    size_t o = (size_t)(bm + tq * 4 + i) * N + bn + tr;
    Chi[o] = hb;
    Clo[o] = f2bf(q - bf2f(hb));
  }
}

// ---------------- K5: fused scores + softmax + ctx ----------------
// Block (b, lh): scores S[64 l][256 r] = QW[lh] @ img[b]^T. B (img) reg-loaded
// f32, cvt_pk -> bf16 hi/lo LDS (64-B rows, swizzled: 2-way conflict-free).
// Counted vmcnt(5), 3 bufs. Then in-register softmax; P -> swizzled LDS;
// ctx = P @ img[b] (transpose-staged). 512 threads = 8 waves (2x4 over 64x256).
__global__ __launch_bounds__(512, 2) void k_fused(
    const unsigned short* __restrict__ QWh, const unsigned short* __restrict__ QWl,
    const float* __restrict__ img, unsigned short* __restrict__ Cp) {
  // bufs 0/40960/81920, each 40 KB: Ah@0 (4K), Al@4096 (4K), Bh@8192 (16K),
  // Bl@24576 (16K). After scores: P@81920 (32K), RMAX@114688, RSUM@115712.
  // ctx bufs 0/16384/32768 (16 KB each) live in buf0/buf1 space.
  __shared__ __attribute__((aligned(16))) char lds[122880];
  int tid = threadIdx.x, l = tid & 63, w = tid >> 6;
  int wm = w >> 2, wn = w & 3;              // 2 x 4 wave grid
  int lr = l & 15, lk8 = l >> 4;
  int sF = (lr >> 1) & 3;
  int rh = lk8 * 4;
  int bid = blockIdx.x;
  int xcd = bid & 7, loc = bid >> 3;
  int b = xcd * 16 + (loc >> 1);
  int lh = loc & 1;
  const int Poff = 81920, RMAX = 114688, RSUM = 115712;

  // ---- scores staging setup ----
  int arow = (w & 3) * 16 + (l >> 2);
  int achk = (l & 3) ^ ((arow >> 1) & 3);
  const unsigned short* aW = (w < 4) ? QWh : QWl;
  const unsigned short* asrc = aW + (size_t)(lh * 64 + arow) * 1024 + achk * 8;
  int aOff = ((w < 4) ? 0 : 4096) + (w & 3) * 1024;
  // B reg staging: thread covers row tid>>1 (0..255), 16 k (chunks c0,c1)
  int brow = tid >> 1;
  int c0 = 2 * (tid & 1), c1 = c0 + 1, sw = (brow >> 1) & 3;
  const float* gBr = img + ((size_t)b * 256 + brow) * 1024 + (tid & 1) * 16;
  int bByte0 = brow * 64 + ((c0 ^ sw) << 4);
  int bByte1 = brow * 64 + ((c1 ^ sw) << 4);

  char* scur = &lds[0];
  char* snxt = &lds[40960];
  char* snx2 = &lds[81920];
  f32x4 vA0, vA1, vA2, vA3, vB0, vB1, vB2, vB3;
  f32x4 acc[2][4] = {};

#define SC_LOADB(K0, R0, R1, R2, R3) { \
    R0 = *(const f32x4*)(gBr + (K0)); \
    R1 = *(const f32x4*)(gBr + (K0) + 4); \
    R2 = *(const f32x4*)(gBr + (K0) + 8); \
    R3 = *(const f32x4*)(gBr + (K0) + 12); }

#define SC_CONV(DST, V0, V1, V2, V3) { \
    unsigned h0 = cvtpk((V0)[0], (V0)[1]), h1 = cvtpk((V0)[2], (V0)[3]); \
    unsigned h2 = cvtpk((V1)[0], (V1)[1]), h3 = cvtpk((V1)[2], (V1)[3]); \
    unsigned g0 = cvtpk((V2)[0], (V2)[1]), g1 = cvtpk((V2)[2], (V2)[3]); \
    unsigned g2 = cvtpk((V3)[0], (V3)[1]), g3 = cvtpk((V3)[2], (V3)[3]); \
    unsigned q0 = cvtpk((V0)[0] - bflo_f(h0), (V0)[1] - bfhi_f(h0)); \
    unsigned q1 = cvtpk((V0)[2] - bflo_f(h1), (V0)[3] - bfhi_f(h1)); \
    unsigned q2 = cvtpk((V1)[0] - bflo_f(h2), (V1)[1] - bfhi_f(h2)); \
    unsigned q3 = cvtpk((V1)[2] - bflo_f(h3), (V1)[3] - bfhi_f(h3)); \
    unsigned r0 = cvtpk((V2)[0] - bflo_f(g0), (V2)[1] - bfhi_f(g0)); \
    unsigned r1 = cvtpk((V2)[2] - bflo_f(g1), (V2)[3] - bfhi_f(g1)); \
    unsigned r2 = cvtpk((V3)[0] - bflo_f(g2), (V3)[1] - bfhi_f(g2)); \
    unsigned r3 = cvtpk((V3)[2] - bflo_f(g3), (V3)[3] - bfhi_f(g3)); \
    *(s16x8*)((DST) + 8192 + bByte0) = pk4(h0, h1, h2, h3); \
    *(s16x8*)((DST) + 8192 + bByte1) = pk4(g0, g1, g2, g3); \
    *(s16x8*)((DST) + 24576 + bByte0) = pk4(q0, q1, q2, q3); \
    *(s16x8*)((DST) + 24576 + bByte1) = pk4(r0, r1, r2, r3); }

#define SC_COMPUTE(BUF) { \
    s16x8 ah[2], al2[2], bh[4], bl[4]; \
    _Pragma("unroll") \
    for (int i = 0; i < 2; i++) { \
      int row = wm * 32 + i * 16 + lr; \
      int byte = row * 64 + ((lk8 ^ sF) << 4); \
      ah[i] = *(const s16x8*)((BUF) + byte); \
      al2[i] = *(const s16x8*)((BUF) + 4096 + byte); \
    } \
    _Pragma("unroll") \
    for (int j = 0; j < 4; j++) { \
      int n = wn * 64 + j * 16 + lr; \
      int byte = n * 64 + ((lk8 ^ sF) << 4); \
      bh[j] = *(const s16x8*)((BUF) + 8192 + byte); \
      bl[j] = *(const s16x8*)((BUF) + 24576 + byte); \
    } \
    __builtin_amdgcn_s_setprio(1); \
    _Pragma("unroll") \
    for (int i = 0; i < 2; i++) \
      _Pragma("unroll") \
      for (int j = 0; j < 4; j++) { \
        acc[i][j] = __builtin_amdgcn_mfma_f32_16x16x32_bf16(ah[i], bh[j], acc[i][j], 0, 0, 0); \
        acc[i][j] = __builtin_amdgcn_mfma_f32_16x16x32_bf16(ah[i], bl[j], acc[i][j], 0, 0, 0); \
        acc[i][j] = __builtin_amdgcn_mfma_f32_16x16x32_bf16(al2[i], bh[j], acc[i][j], 0, 0, 0); \
      } \
    __builtin_amdgcn_s_setprio(0); }

#define SC_STEP(T, CI0, CI1, CI2, CI3, CO0, CO1, CO2, CO3) { \
    int kn = ((T) + 2) * 32; \
    SC_LOADB(kn, CO0, CO1, CO2, CO3); \
    SFENCE(); \
    gload_lds16(asrc + kn, snx2 + aOff); \
    SFENCE(); \
    SC_COMPUTE(scur); \
    SC_CONV(snxt, CI0, CI1, CI2, CI3); \
    VMCNT(5); \
    LGKM0(); \
    SBAR(); \
    SFENCE(); \
    { char* t_ = scur; scur = snxt; snxt = snx2; snx2 = t_; } }

  // prologue: tiles 0,1
  SC_LOADB(0, vA0, vA1, vA2, vA3);
  SFENCE();
  gload_lds16(asrc, scur + aOff);
  SFENCE();
  SC_LOADB(32, vB0, vB1, vB2, vB3);
  SFENCE();
  gload_lds16(asrc + 32, snxt + aOff);
  SFENCE();
  SC_CONV(scur, vA0, vA1, vA2, vA3);
  VMCNT(5);
  LGKM0();
  SBAR();
  SFENCE();
#pragma unroll 1
  for (int it = 0; it < 15; ++it) {
    SC_STEP(2 * it,     vB0, vB1, vB2, vB3, vA0, vA1, vA2, vA3);
    SC_STEP(2 * it + 1, vA0, vA1, vA2, vA3, vB0, vB1, vB2, vB3);
  }
  // step 30: compute + write B(31), drain
  SC_COMPUTE(scur);
  SC_CONV(snxt, vB0, vB1, vB2, vB3);
  VMCNT(0);
  LGKM0();
  SBAR();
  SFENCE();
  { char* t_ = scur; scur = snxt; snxt = snx2; snx2 = t_; }
  // step 31
  SC_COMPUTE(scur);
  SBAR();
  SFENCE();
#undef SC_STEP
#undef SC_COMPUTE
#undef SC_CONV
#undef SC_LOADB

  // ---- softmax over r=256 (rows = caption l), in-register + LDS reduce ----
  {
#pragma unroll
    for (int i = 0; i < 2; i++)
#pragma unroll
      for (int q = 0; q < 4; q++) {
        float m = fmaxf(fmaxf(acc[i][0][q], acc[i][1][q]),
                        fmaxf(acc[i][2][q], acc[i][3][q]));
#pragma unroll
        for (int s = 1; s < 16; s <<= 1) m = fmaxf(m, __shfl_xor(m, s, 64));
        if (lr == 0)
          *(float*)(lds + RMAX + (wm * 32 + i * 16 + rh + q) * 16 + wn * 4) = m;
      }
    LGKM0();
    SBAR();
#pragma unroll
    for (int i = 0; i < 2; i++)
#pragma unroll
      for (int q = 0; q < 4; q++) {
        int row = wm * 32 + i * 16 + rh + q;
        const float* rm = (const float*)(lds + RMAX + row * 16);
        float g = fmaxf(fmaxf(rm[0], rm[1]), fmaxf(rm[2], rm[3]));
        float ps = 0.f;
#pragma unroll
        for (int j = 0; j < 4; j++) {
          float e = __expf(acc[i][j][q] - g);
          acc[i][j][q] = e;
          ps += e;
        }
#pragma unroll
        for (int s = 1; s < 16; s <<= 1) ps += __shfl_xor(ps, s, 64);
        if (lr == 0) *(float*)(lds + RSUM + row * 16 + wn * 4) = ps;
      }
    LGKM0();
    SBAR();
#pragma unroll
    for (int i = 0; i < 2; i++)
#pragma unroll
      for (int q = 0; q < 4; q++) {
        int row = wm * 32 + i * 16 + rh + q;
        const float* rs = (const float*)(lds + RSUM + row * 16);
        float sc = 0.03125f / (rs[0] + rs[1] + rs[2] + rs[3]);
#pragma unroll
        for (int j = 0; j < 4; j++) {
          int col = wn * 64 + j * 16 + lr;
          int byte = Poff + row * 512 +
                     (((col >> 3) ^ ((row & 7) << 2)) << 4) + (col & 7) * 2;
          *(unsigned short*)(lds + byte) = f2bf(acc[i][j][q] * sc);
        }
      }
    LGKM0();
    SBAR();
    SFENCE();
  }

  // ---- ctx phase: ctx[64 l][1024 d] = P @ img[b], 32 steps (4 d-chunks x 8 k) ----
  {
    int u = tid & 15, dc = tid >> 4;        // u: r-pair, dc: 8-d group (0..31)
    const float* gva = img + ((size_t)b * 256 + 2 * u) * 1024 + dc * 8;
    const float* gvb = gva + 1024;
    char* ccur = &lds[0];
    char* cnxt = &lds[16384];
    char* cnx2 = &lds[32768];
    f32x4 vAa, vAb, vAc, vAd, vBa, vBb, vBc, vBd;
    f32x4 acc2[2][4] = {};

#define CTX_LOAD(T, Ra, Rb, Rc, Rd) { \
    int tt = ((T) < 32) ? (T) : 31; \
    size_t off = (size_t)((tt & 7) * 32) * 1024 + (tt >> 3) * 256; \
    Ra = *(const f32x4*)(gva + off); \
    Rb = *(const f32x4*)(gva + off + 4); \
    Rc = *(const f32x4*)(gvb + off); \
    Rd = *(const f32x4*)(gvb + off + 4); }

#define CTX_CONV(DST, Ra, Rb, Rc, Rd) { \
    _Pragma("unroll") \
    for (int j = 0; j < 8; j++) { \
      float x0 = (j < 4) ? (Ra)[j & 3] : (Rb)[j & 3]; \
      float x1 = (j < 4) ? (Rc)[j & 3] : (Rd)[j & 3]; \
      int dd = dc * 8 + j; \
      unsigned int w32 = cvtpk(x0, x1); \
      int byte = dd * 64 + ((4 * u) ^ (((dd >> 1) & 3) << 4)); \
      *(unsigned int*)((DST) + byte) = w32; \
    } }

#define CTX_STEP(T, CIa, CIb, CIc, CId, COa, COb, COc, COd) { \
    CTX_LOAD((T) + 2, COa, COb, COc, COd); \
    SFENCE(); \
    s16x8 af[2], bf[4]; \
    _Pragma("unroll") \
    for (int i = 0; i < 2; i++) { \
      int row = wm * 32 + i * 16 + lr; \
      int rc = ((T) & 7) * 4 + lk8; \
      int byte = Poff + row * 512 + ((rc ^ ((row & 7) << 2)) << 4); \
      af[i] = *(const s16x8*)(lds + byte); \
    } \
    _Pragma("unroll") \
    for (int j = 0; j < 4; j++) { \
      int n = wn * 64 + j * 16 + lr; \
      int byte = n * 64 + ((lk8 ^ ((n >> 1) & 3)) << 4); \
      bf[j] = *(const s16x8*)(ccur + byte); \
    } \
    __builtin_amdgcn_s_setprio(1); \
    _Pragma("unroll") \
    for (int i = 0; i < 2; i++) \
      _Pragma("unroll") \
      for (int j = 0; j < 4; j++) \
        acc2[i][j] = __builtin_amdgcn_mfma_f32_16x16x32_bf16(af[i], bf[j], acc2[i][j], 0, 0, 0); \
    __builtin_amdgcn_s_setprio(0); \
    CTX_CONV(cnxt, CIa, CIb, CIc, CId); \
    if (((T) & 7) == 7) { \
      int d0c = ((T) >> 3) * 256; \
      _Pragma("unroll") \
      for (int i = 0; i < 2; i++) \
        _Pragma("unroll") \
        for (int q = 0; q < 4; q++) { \
          int gl = lh * 64 + wm * 32 + i * 16 + rh + q; \
          _Pragma("unroll") \
          for (int j = 0; j < 4; j++) { \
            int gn = d0c + wn * 64 + j * 16 + lr; \
            Cp[((size_t)b * 128 + gl) * 1024 + gn] = f2bf(acc2[i][j][q]); \
            acc2[i][j][q] = 0.f; \
          } \
        } \
    } \
    VMCNT(4); \
    LGKM0(); \
    SBAR(); \
    SFENCE(); \
    { char* t_ = ccur; ccur = cnxt; cnxt = cnx2; cnx2 = t_; } }

    CTX_LOAD(0, vAa, vAb, vAc, vAd);
    SFENCE();
    CTX_LOAD(1, vBa, vBb, vBc, vBd);
    SFENCE();
    CTX_CONV(ccur, vAa, vAb, vAc, vAd);
    VMCNT(4);
    LGKM0();
    SBAR();
    SFENCE();
#pragma unroll 1
    for (int it = 0; it < 16; ++it) {
      int t0 = 2 * it;
      CTX_STEP(t0,     vBa, vBb, vBc, vBd, vAa, vAb, vAc, vAd);
      CTX_STEP(t0 + 1, vAa, vAb, vAc, vAd, vBa, vBb, vBc, vBd);
    }
#undef CTX_STEP
#undef CTX_CONV
#undef CTX_LOAD
  }
}

// ---------------- K10: out[m][n] = sum_k ctx[m][k]*Wv[n][k] + bv[n]/32 ----------------
// 256x128 tile, 512 threads (8 waves 4x2), 3-buf counted vmcnt(3).
// Grid 512 = 64 M-tiles x 8 N-tiles, XCD-grouped. M=16384, N=1024, K=1024.
__global__ __launch_bounds__(512, 2) void k_gemm_out(
    const unsigned short* __restrict__ A, const unsigned short* __restrict__ Bm,
    const float* __restrict__ bv, float* __restrict__ Out) {
  // per buf (24 KB): A @0 (16K: 256 rows x 64B), B @16384 (8K: 128 rows)
  __shared__ __attribute__((aligned(16))) char lds[73728];
  int tid = threadIdx.x, l = tid & 63, w = tid >> 6;   // 8 waves
  int wm = w >> 1, wn = w & 1;                          // 4 x 2
  int rid = blockIdx.x;
  int xcd = rid & 7, lid = rid >> 3;
  int bm = (xcd * 8 + (lid >> 3)) * 256;
  int bn = (lid & 7) * 128;
  int lr = l & 15, lk8 = l >> 4;
  int sF = (lr >> 1) & 3;
  int srow = tid >> 2;                      // 0..127
  int swz = (tid & 3) ^ ((tid >> 3) & 3);
  const unsigned short* a0 = A + (size_t)(bm + srow) * 1024 + swz * 8;
  const unsigned short* a1 = A + (size_t)(bm + 128 + srow) * 1024 + swz * 8;
  const unsigned short* b0 = Bm + (size_t)(bn + srow) * 1024 + swz * 8;
  char* cur = &lds[0];
  char* nxt = &lds[24576];
  char* nx2 = &lds[49152];
  f32x4 acc[4][4] = {};

#define OUT_STAGE(KN, BUF) { \
    gload_lds16(a0 + (KN), (BUF) + w * 1024); \
    gload_lds16(a1 + (KN), (BUF) + 8192 + w * 1024); \
    gload_lds16(b0 + (KN), (BUF) + 16384 + w * 1024); }

#define OUT_STEP(T) { \
    int kn = (((T) + 2 < 32) ? (T) + 2 : 31) * 32; \
    OUT_STAGE(kn, nx2); \
    SFENCE(); \
    s16x8 af[4], bf[4]; \
    _Pragma("unroll") \
    for (int i = 0; i < 4; i++) { \
      int byte = (wm * 64 + i * 16 + lr) * 64 + ((lk8 ^ sF) << 4); \
      af[i] = *(const s16x8*)(cur + byte); \
    } \
    _Pragma("unroll") \
    for (int i = 0; i < 4; i++) { \
      int byte = 16384 + (wn * 64 + i * 16 + lr) * 64 + ((lk8 ^ sF) << 4); \
      bf[i] = *(const s16x8*)(cur + byte); \
    } \
    __builtin_amdgcn_s_setprio(1); \
    _Pragma("unroll") \
    for (int i = 0; i < 4; i++) \
      _Pragma("unroll") \
      for (int j = 0; j < 4; j++) \
        acc[i][j] = __builtin_amdgcn_mfma_f32_16x16x32_bf16(af[i], bf[j], acc[i][j], 0, 0, 0); \
    __builtin_amdgcn_s_setprio(0); \
    VMCNT(3); \
    SBAR(); \
    SFENCE(); \
    { char* t_ = cur; cur = nxt; nxt = nx2; nx2 = t_; } }

  OUT_STAGE(0, cur);
  SFENCE();
  OUT_STAGE(32, nxt);
  SFENCE();
  VMCNT(3);
  SBAR();
  SFENCE();

#pragma unroll 1
  for (int t = 0; t < 32; ++t) {
    OUT_STEP(t);
  }

  int rh = (l >> 4) * 4;
#pragma unroll
  for (int i = 0; i < 4; i++)
#pragma unroll
    for (int q = 0; q < 4; q++) {
      int gm = bm + wm * 64 + i * 16 + rh + q;
#pragma unroll
      for (int j = 0; j < 4; j++) {
        int gn = bn + wn * 64 + j * 16 + lr;
        Out[(size_t)gm * 1024 + gn] = acc[i][j][q] + 0.03125f * bv[gn];
      }
    }
#undef OUT_STEP
#undef OUT_STAGE
}

extern "C" void kernel_launch(void* const* d_in, const int* in_sizes, int n_in,
                              void* d_out, int out_size, void* d_ws, size_t ws_size,
                              hipStream_t stream) {
  const float* cap = (const float*)d_in[0];
  const float* img = (const float*)d_in[1];
  const float* Wq  = (const float*)d_in[2];
  const float* bq  = (const float*)d_in[3];
  const float* Wk  = (const float*)d_in[4];
  // d_in[5] = bk: constant across r -> cancels in softmax. Unused.
  const float* Wv  = (const float*)d_in[6];
  const float* bv  = (const float*)d_in[7];
  float* out = (float*)d_out;

  char* ws = (char*)d_ws;
  if (ws_size < 36700160ull) return;  // fail loudly (output stays poisoned)
  unsigned short* ctx = (unsigned short*)(ws);               // 32 MB
  float*          Qb  = (float*)(ws + 33554432);             // 512 KB
  unsigned short* QWh = (unsigned short*)(ws + 34078720);    // 256 KB
  unsigned short* QWl = (unsigned short*)(ws + 34340864);    // 256 KB
  unsigned short* Wvh = (unsigned short*)(ws + 34603008);    //   2 MB

  k_convert_hi<<<1024, 256, 0, stream>>>(Wv, Wvh, 1048576 / 4);
  // Q = cap @ Wq^T + bq  (f32)
  k_gemm_f32_tn<<<dim3(4, 32), 256, 0, stream>>>(cap, Wq, bq, Qb, 128, 1024, 1024);
  // QW = Q @ Wk  (f32 -> bf16 hi/lo)
  k_gemm_f32_nn_split<<<dim3(4, 32), 256, 0, stream>>>(Qb, Wk, QWh, QWl, 128, 1024, 1024);
  // fused: scores (3-pass split bf16, bf16-staged B) + softmax/32 + ctx
  k_fused<<<256, 512, 0, stream>>>(QWh, QWl, img, ctx);
  // out = ctx @ Wv^T + bv/32  (256x128 counted-vmcnt pipeline)
  k_gemm_out<<<512, 512, 0, stream>>>(ctx, Wvh, bv, out);
}

// Round 16
// 157.525 us; speedup vs baseline: 1.5357x; 1.3375x over previous
//
#include <hip/hip_runtime.h>
#include <stdint.h>

typedef __attribute__((ext_vector_type(4))) float  f32x4;
typedef __attribute__((ext_vector_type(8))) short  s16x8;
typedef __attribute__((ext_vector_type(4))) short  s16x4;
typedef __attribute__((ext_vector_type(4))) unsigned int u32x4;
typedef __attribute__((ext_vector_type(2))) unsigned int u32x2;

__device__ __forceinline__ unsigned short f2bf(float x) {
  union { float f; unsigned int u; } a; a.f = x;
  unsigned int lsb = (a.u >> 16) & 1u;
  a.u += 0x7fffu + lsb;                    // round-to-nearest-even
  return (unsigned short)(a.u >> 16);
}
__device__ __forceinline__ float bf2f(unsigned short h) {
  union { unsigned int u; float f; } a; a.u = ((unsigned int)h) << 16; return a.f;
}
// HW packed f32->bf16 RNE: lo16 = bf16(a), hi16 = bf16(b). Bit-identical to f2bf.
__device__ __forceinline__ unsigned int cvtpk(float a, float b) {
  unsigned int d;
  asm("v_cvt_pk_bf16_f32 %0, %1, %2" : "=v"(d) : "v"(a), "v"(b));
  return d;
}
__device__ __forceinline__ float bflo_f(unsigned int u) {
  union { unsigned int u; float f; } x; x.u = u << 16; return x.f;
}
__device__ __forceinline__ float bfhi_f(unsigned int u) {
  union { unsigned int u; float f; } x; x.u = u & 0xffff0000u; return x.f;
}
__device__ __forceinline__ s16x8 pk4(unsigned a, unsigned b, unsigned c, unsigned d) {
  union { u32x4 u; s16x8 s; } x;
  u32x4 v = {a, b, c, d}; x.u = v; return x.s;
}

__device__ __forceinline__ void gload_lds16(const void* g, void* s) {
  __builtin_amdgcn_global_load_lds(
      (__attribute__((address_space(1))) void*)g,
      (__attribute__((address_space(3))) void*)s, 16, 0, 0);
}

#define VMCNT(N) asm volatile("s_waitcnt vmcnt(" #N ")" ::: "memory")
#define LGKM0()  asm volatile("s_waitcnt lgkmcnt(0)" ::: "memory")
#define SBAR()   __builtin_amdgcn_s_barrier()
#define SFENCE() __builtin_amdgcn_sched_barrier(0)

// ---------------- K1: Q partials (f32 TN, K-split 4) ----------------
// Qp[ks][128][1024]: Qp[ks][m][n] = sum_{k in ks-chunk} cap[m][k] * Wq[n][k]
__global__ __launch_bounds__(256) void k_q_part(
    const float* __restrict__ A, const float* __restrict__ Bm,
    float* __restrict__ Qp) {
  __shared__ float As[32][33], Bs[32][33];
  int tid = threadIdx.x;
  int bm = blockIdx.x * 32, bn = blockIdx.y * 32;
  int kbase = blockIdx.z * 256;
  int tr = tid & 31, tq = tid >> 5;
  float acc[4] = {0.f, 0.f, 0.f, 0.f};
  for (int k0 = kbase; k0 < kbase + 256; k0 += 32) {
#pragma unroll
    for (int i = 0; i < 4; i++) {
      int idx = tid + i * 256;
      int r = idx >> 5, c = idx & 31;
      As[r][c] = A[(size_t)(bm + r) * 1024 + k0 + c];
      Bs[r][c] = Bm[(size_t)(bn + r) * 1024 + k0 + c];
    }
    __syncthreads();
#pragma unroll
    for (int kk = 0; kk < 32; kk++) {
      float b = Bs[tr][kk];
#pragma unroll
      for (int i = 0; i < 4; i++) acc[i] += As[tq * 4 + i][kk] * b;
    }
    __syncthreads();
  }
#pragma unroll
  for (int i = 0; i < 4; i++)
    Qp[(size_t)blockIdx.z * 131072 + (size_t)(bm + tq * 4 + i) * 1024 + bn + tr] = acc[i];
}

// ---------------- K2: QW partials (f32 NN, K-split 4) ----------------
// A[m][k] = sum_p Qp[p][m][k] + bq[k];  QWp[ks][m][n] = sum_{k in chunk} A*Wk[k][n]
__global__ __launch_bounds__(256) void k_qw_part(
    const float* __restrict__ Qp, const float* __restrict__ bq,
    const float* __restrict__ Wk, float* __restrict__ QWp) {
  __shared__ float As[32][33], Bs[32][33];
  int tid = threadIdx.x;
  int bm = blockIdx.x * 32, bn = blockIdx.y * 32;
  int kbase = blockIdx.z * 256;
  int tr = tid & 31, tq = tid >> 5;
  float acc[4] = {0.f, 0.f, 0.f, 0.f};
  for (int k0 = kbase; k0 < kbase + 256; k0 += 32) {
#pragma unroll
    for (int i = 0; i < 4; i++) {
      int idx = tid + i * 256;
      int r = idx >> 5, c = idx & 31;
      size_t qa = (size_t)(bm + r) * 1024 + k0 + c;
      float s = (Qp[qa] + Qp[qa + 131072]) + (Qp[qa + 262144] + Qp[qa + 393216]);
      As[r][c] = s + bq[k0 + c];
      Bs[r][c] = Wk[(size_t)(k0 + r) * 1024 + bn + c];
    }
    __syncthreads();
#pragma unroll
    for (int kk = 0; kk < 32; kk++) {
      float b = Bs[kk][tr];
#pragma unroll
      for (int i = 0; i < 4; i++) acc[i] += As[tq * 4 + i][kk] * b;
    }
    __syncthreads();
  }
#pragma unroll
  for (int i = 0; i < 4; i++)
    QWp[(size_t)blockIdx.z * 131072 + (size_t)(bm + tq * 4 + i) * 1024 + bn + tr] = acc[i];
}

// ---------------- K3: reduce QW partials -> hi/lo split; + convert Wv -> bf16 ----------------
// blocks 0..127: QW reduce+split (131072 elems, 4/thread).
// blocks 128..1151: Wv convert (1048576 elems, 4/thread).
__global__ __launch_bounds__(256) void k_reduce_convert(
    const float* __restrict__ QWp, const float* __restrict__ Wv,
    unsigned short* __restrict__ QWh, unsigned short* __restrict__ QWl,
    unsigned short* __restrict__ Wvh) {
  int bid = blockIdx.x;
  if (bid < 128) {
    int i = bid * 256 + threadIdx.x;        // f32x4 index, 32768 total
    const f32x4* P4 = (const f32x4*)QWp;
    f32x4 a = P4[i], b = P4[i + 32768], c = P4[i + 65536], d = P4[i + 98304];
    f32x4 s;
#pragma unroll
    for (int j = 0; j < 4; j++) s[j] = (a[j] + b[j]) + (c[j] + d[j]);
    unsigned h0 = cvtpk(s[0], s[1]), h1 = cvtpk(s[2], s[3]);
    unsigned l0 = cvtpk(s[0] - bflo_f(h0), s[1] - bfhi_f(h0));
    unsigned l1 = cvtpk(s[2] - bflo_f(h1), s[3] - bfhi_f(h1));
    u32x2 hv = {h0, h1}, lv = {l0, l1};
    ((u32x2*)QWh)[i] = hv;
    ((u32x2*)QWl)[i] = lv;
  } else {
    int i = (bid - 128) * 256 + threadIdx.x;  // f32x4 index, 262144 total
    f32x4 v = ((const f32x4*)Wv)[i];
    u32x2 h;
    h[0] = cvtpk(v[0], v[1]);
    h[1] = cvtpk(v[2], v[3]);
    ((u32x2*)Wvh)[i] = h;
  }
}

// ---------------- K5: fused scores + softmax + ctx ----------------
// Block (b, lh): scores S[64 l][256 r] = QW[lh] @ img[b]^T. B (img) reg-loaded
// f32, cvt_pk -> bf16 hi/lo LDS (64-B rows, swizzled: 2-way conflict-free).
// Counted vmcnt(5), 3 bufs. Then in-register softmax; P -> swizzled LDS;
// ctx = P @ img[b] (transpose-staged). 512 threads = 8 waves (2x4 over 64x256).
__global__ __launch_bounds__(512, 2) void k_fused(
    const unsigned short* __restrict__ QWh, const unsigned short* __restrict__ QWl,
    const float* __restrict__ img, unsigned short* __restrict__ Cp) {
  // bufs 0/40960/81920, each 40 KB: Ah@0 (4K), Al@4096 (4K), Bh@8192 (16K),
  // Bl@24576 (16K). After scores: P@81920 (32K), RMAX@114688, RSUM@115712.
  // ctx bufs 0/16384/32768 (16 KB each) live in buf0/buf1 space.
  __shared__ __attribute__((aligned(16))) char lds[122880];
  int tid = threadIdx.x, l = tid & 63, w = tid >> 6;
  int wm = w >> 2, wn = w & 3;              // 2 x 4 wave grid
  int lr = l & 15, lk8 = l >> 4;
  int sF = (lr >> 1) & 3;
  int rh = lk8 * 4;
  int bid = blockIdx.x;
  int xcd = bid & 7, loc = bid >> 3;
  int b = xcd * 16 + (loc >> 1);
  int lh = loc & 1;
  const int Poff = 81920, RMAX = 114688, RSUM = 115712;

  // ---- scores staging setup ----
  int arow = (w & 3) * 16 + (l >> 2);
  int achk = (l & 3) ^ ((arow >> 1) & 3);
  const unsigned short* aW = (w < 4) ? QWh : QWl;
  const unsigned short* asrc = aW + (size_t)(lh * 64 + arow) * 1024 + achk * 8;
  int aOff = ((w < 4) ? 0 : 4096) + (w & 3) * 1024;
  // B reg staging: thread covers row tid>>1 (0..255), 16 k (chunks c0,c1)
  int brow = tid >> 1;
  int c0 = 2 * (tid & 1), c1 = c0 + 1, sw = (brow >> 1) & 3;
  const float* gBr = img + ((size_t)b * 256 + brow) * 1024 + (tid & 1) * 16;
  int bByte0 = brow * 64 + ((c0 ^ sw) << 4);
  int bByte1 = brow * 64 + ((c1 ^ sw) << 4);

  char* scur = &lds[0];
  char* snxt = &lds[40960];
  char* snx2 = &lds[81920];
  f32x4 vA0, vA1, vA2, vA3, vB0, vB1, vB2, vB3;
  f32x4 acc[2][4] = {};

#define SC_LOADB(K0, R0, R1, R2, R3) { \
    R0 = *(const f32x4*)(gBr + (K0)); \
    R1 = *(const f32x4*)(gBr + (K0) + 4); \
    R2 = *(const f32x4*)(gBr + (K0) + 8); \
    R3 = *(const f32x4*)(gBr + (K0) + 12); }

#define SC_CONV(DST, V0, V1, V2, V3) { \
    unsigned h0 = cvtpk((V0)[0], (V0)[1]), h1 = cvtpk((V0)[2], (V0)[3]); \
    unsigned h2 = cvtpk((V1)[0], (V1)[1]), h3 = cvtpk((V1)[2], (V1)[3]); \
    unsigned g0 = cvtpk((V2)[0], (V2)[1]), g1 = cvtpk((V2)[2], (V2)[3]); \
    unsigned g2 = cvtpk((V3)[0], (V3)[1]), g3 = cvtpk((V3)[2], (V3)[3]); \
    unsigned q0 = cvtpk((V0)[0] - bflo_f(h0), (V0)[1] - bfhi_f(h0)); \
    unsigned q1 = cvtpk((V0)[2] - bflo_f(h1), (V0)[3] - bfhi_f(h1)); \
    unsigned q2 = cvtpk((V1)[0] - bflo_f(h2), (V1)[1] - bfhi_f(h2)); \
    unsigned q3 = cvtpk((V1)[2] - bflo_f(h3), (V1)[3] - bfhi_f(h3)); \
    unsigned r0 = cvtpk((V2)[0] - bflo_f(g0), (V2)[1] - bfhi_f(g0)); \
    unsigned r1 = cvtpk((V2)[2] - bflo_f(g1), (V2)[3] - bfhi_f(g1)); \
    unsigned r2 = cvtpk((V3)[0] - bflo_f(g2), (V3)[1] - bfhi_f(g2)); \
    unsigned r3 = cvtpk((V3)[2] - bflo_f(g3), (V3)[3] - bfhi_f(g3)); \
    *(s16x8*)((DST) + 8192 + bByte0) = pk4(h0, h1, h2, h3); \
    *(s16x8*)((DST) + 8192 + bByte1) = pk4(g0, g1, g2, g3); \
    *(s16x8*)((DST) + 24576 + bByte0) = pk4(q0, q1, q2, q3); \
    *(s16x8*)((DST) + 24576 + bByte1) = pk4(r0, r1, r2, r3); }

#define SC_COMPUTE(BUF) { \
    s16x8 ah[2], al2[2], bh[4], bl[4]; \
    _Pragma("unroll") \
    for (int i = 0; i < 2; i++) { \
      int row = wm * 32 + i * 16 + lr; \
      int byte = row * 64 + ((lk8 ^ sF) << 4); \
      ah[i] = *(const s16x8*)((BUF) + byte); \
      al2[i] = *(const s16x8*)((BUF) + 4096 + byte); \
    } \
    _Pragma("unroll") \
    for (int j = 0; j < 4; j++) { \
      int n = wn * 64 + j * 16 + lr; \
      int byte = n * 64 + ((lk8 ^ sF) << 4); \
      bh[j] = *(const s16x8*)((BUF) + 8192 + byte); \
      bl[j] = *(const s16x8*)((BUF) + 24576 + byte); \
    } \
    __builtin_amdgcn_s_setprio(1); \
    _Pragma("unroll") \
    for (int i = 0; i < 2; i++) \
      _Pragma("unroll") \
      for (int j = 0; j < 4; j++) { \
        acc[i][j] = __builtin_amdgcn_mfma_f32_16x16x32_bf16(ah[i], bh[j], acc[i][j], 0, 0, 0); \
        acc[i][j] = __builtin_amdgcn_mfma_f32_16x16x32_bf16(ah[i], bl[j], acc[i][j], 0, 0, 0); \
        acc[i][j] = __builtin_amdgcn_mfma_f32_16x16x32_bf16(al2[i], bh[j], acc[i][j], 0, 0, 0); \
      } \
    __builtin_amdgcn_s_setprio(0); }

#define SC_STEP(T, CI0, CI1, CI2, CI3, CO0, CO1, CO2, CO3) { \
    int kn = ((T) + 2) * 32; \
    SC_LOADB(kn, CO0, CO1, CO2, CO3); \
    SFENCE(); \
    gload_lds16(asrc + kn, snx2 + aOff); \
    SFENCE(); \
    SC_COMPUTE(scur); \
    SC_CONV(snxt, CI0, CI1, CI2, CI3); \
    VMCNT(5); \
    LGKM0(); \
    SBAR(); \
    SFENCE(); \
    { char* t_ = scur; scur = snxt; snxt = snx2; snx2 = t_; } }

  // prologue: tiles 0,1
  SC_LOADB(0, vA0, vA1, vA2, vA3);
  SFENCE();
  gload_lds16(asrc, scur + aOff);
  SFENCE();
  SC_LOADB(32, vB0, vB1, vB2, vB3);
  SFENCE();
  gload_lds16(asrc + 32, snxt + aOff);
  SFENCE();
  SC_CONV(scur, vA0, vA1, vA2, vA3);
  VMCNT(5);
  LGKM0();
  SBAR();
  SFENCE();
#pragma unroll 1
  for (int it = 0; it < 15; ++it) {
    SC_STEP(2 * it,     vB0, vB1, vB2, vB3, vA0, vA1, vA2, vA3);
    SC_STEP(2 * it + 1, vA0, vA1, vA2, vA3, vB0, vB1, vB2, vB3);
  }
  // step 30: compute + write B(31), drain
  SC_COMPUTE(scur);
  SC_CONV(snxt, vB0, vB1, vB2, vB3);
  VMCNT(0);
  LGKM0();
  SBAR();
  SFENCE();
  { char* t_ = scur; scur = snxt; snxt = snx2; snx2 = t_; }
  // step 31
  SC_COMPUTE(scur);
  SBAR();
  SFENCE();
#undef SC_STEP
#undef SC_COMPUTE
#undef SC_CONV
#undef SC_LOADB

  // ---- softmax over r=256 (rows = caption l), in-register + LDS reduce ----
  {
#pragma unroll
    for (int i = 0; i < 2; i++)
#pragma unroll
      for (int q = 0; q < 4; q++) {
        float m = fmaxf(fmaxf(acc[i][0][q], acc[i][1][q]),
                        fmaxf(acc[i][2][q], acc[i][3][q]));
#pragma unroll
        for (int s = 1; s < 16; s <<= 1) m = fmaxf(m, __shfl_xor(m, s, 64));
        if (lr == 0)
          *(float*)(lds + RMAX + (wm * 32 + i * 16 + rh + q) * 16 + wn * 4) = m;
      }
    LGKM0();
    SBAR();
#pragma unroll
    for (int i = 0; i < 2; i++)
#pragma unroll
      for (int q = 0; q < 4; q++) {
        int row = wm * 32 + i * 16 + rh + q;
        const float* rm = (const float*)(lds + RMAX + row * 16);
        float g = fmaxf(fmaxf(rm[0], rm[1]), fmaxf(rm[2], rm[3]));
        float ps = 0.f;
#pragma unroll
        for (int j = 0; j < 4; j++) {
          float e = __expf(acc[i][j][q] - g);
          acc[i][j][q] = e;
          ps += e;
        }
#pragma unroll
        for (int s = 1; s < 16; s <<= 1) ps += __shfl_xor(ps, s, 64);
        if (lr == 0) *(float*)(lds + RSUM + row * 16 + wn * 4) = ps;
      }
    LGKM0();
    SBAR();
#pragma unroll
    for (int i = 0; i < 2; i++)
#pragma unroll
      for (int q = 0; q < 4; q++) {
        int row = wm * 32 + i * 16 + rh + q;
        const float* rs = (const float*)(lds + RSUM + row * 16);
        float sc = 0.03125f / (rs[0] + rs[1] + rs[2] + rs[3]);
#pragma unroll
        for (int j = 0; j < 4; j++) {
          int col = wn * 64 + j * 16 + lr;
          int byte = Poff + row * 512 +
                     (((col >> 3) ^ ((row & 7) << 2)) << 4) + (col & 7) * 2;
          *(unsigned short*)(lds + byte) = f2bf(acc[i][j][q] * sc);
        }
      }
    LGKM0();
    SBAR();
    SFENCE();
  }

  // ---- ctx phase: ctx[64 l][1024 d] = P @ img[b], 32 steps (4 d-chunks x 8 k) ----
  {
    int u = tid & 15, dc = tid >> 4;        // u: r-pair, dc: 8-d group (0..31)
    const float* gva = img + ((size_t)b * 256 + 2 * u) * 1024 + dc * 8;
    const float* gvb = gva + 1024;
    char* ccur = &lds[0];
    char* cnxt = &lds[16384];
    char* cnx2 = &lds[32768];
    f32x4 vAa, vAb, vAc, vAd, vBa, vBb, vBc, vBd;
    f32x4 acc2[2][4] = {};

#define CTX_LOAD(T, Ra, Rb, Rc, Rd) { \
    int tt = ((T) < 32) ? (T) : 31; \
    size_t off = (size_t)((tt & 7) * 32) * 1024 + (tt >> 3) * 256; \
    Ra = *(const f32x4*)(gva + off); \
    Rb = *(const f32x4*)(gva + off + 4); \
    Rc = *(const f32x4*)(gvb + off); \
    Rd = *(const f32x4*)(gvb + off + 4); }

#define CTX_CONV(DST, Ra, Rb, Rc, Rd) { \
    _Pragma("unroll") \
    for (int j = 0; j < 8; j++) { \
      float x0 = (j < 4) ? (Ra)[j & 3] : (Rb)[j & 3]; \
      float x1 = (j < 4) ? (Rc)[j & 3] : (Rd)[j & 3]; \
      int dd = dc * 8 + j; \
      unsigned int w32 = cvtpk(x0, x1); \
      int byte = dd * 64 + ((4 * u) ^ (((dd >> 1) & 3) << 4)); \
      *(unsigned int*)((DST) + byte) = w32; \
    } }

#define CTX_STEP(T, CIa, CIb, CIc, CId, COa, COb, COc, COd) { \
    CTX_LOAD((T) + 2, COa, COb, COc, COd); \
    SFENCE(); \
    s16x8 af[2], bf[4]; \
    _Pragma("unroll") \
    for (int i = 0; i < 2; i++) { \
      int row = wm * 32 + i * 16 + lr; \
      int rc = ((T) & 7) * 4 + lk8; \
      int byte = Poff + row * 512 + ((rc ^ ((row & 7) << 2)) << 4); \
      af[i] = *(const s16x8*)(lds + byte); \
    } \
    _Pragma("unroll") \
    for (int j = 0; j < 4; j++) { \
      int n = wn * 64 + j * 16 + lr; \
      int byte = n * 64 + ((lk8 ^ ((n >> 1) & 3)) << 4); \
      bf[j] = *(const s16x8*)(ccur + byte); \
    } \
    __builtin_amdgcn_s_setprio(1); \
    _Pragma("unroll") \
    for (int i = 0; i < 2; i++) \
      _Pragma("unroll") \
      for (int j = 0; j < 4; j++) \
        acc2[i][j] = __builtin_amdgcn_mfma_f32_16x16x32_bf16(af[i], bf[j], acc2[i][j], 0, 0, 0); \
    __builtin_amdgcn_s_setprio(0); \
    CTX_CONV(cnxt, CIa, CIb, CIc, CId); \
    if (((T) & 7) == 7) { \
      int d0c = ((T) >> 3) * 256; \
      _Pragma("unroll") \
      for (int i = 0; i < 2; i++) \
        _Pragma("unroll") \
        for (int q = 0; q < 4; q++) { \
          int gl = lh * 64 + wm * 32 + i * 16 + rh + q; \
          _Pragma("unroll") \
          for (int j = 0; j < 4; j++) { \
            int gn = d0c + wn * 64 + j * 16 + lr; \
            Cp[((size_t)b * 128 + gl) * 1024 + gn] = f2bf(acc2[i][j][q]); \
            acc2[i][j][q] = 0.f; \
          } \
        } \
    } \
    VMCNT(4); \
    LGKM0(); \
    SBAR(); \
    SFENCE(); \
    { char* t_ = ccur; ccur = cnxt; cnxt = cnx2; cnx2 = t_; } }

    CTX_LOAD(0, vAa, vAb, vAc, vAd);
    SFENCE();
    CTX_LOAD(1, vBa, vBb, vBc, vBd);
    SFENCE();
    CTX_CONV(ccur, vAa, vAb, vAc, vAd);
    VMCNT(4);
    LGKM0();
    SBAR();
    SFENCE();
#pragma unroll 1
    for (int it = 0; it < 16; ++it) {
      int t0 = 2 * it;
      CTX_STEP(t0,     vBa, vBb, vBc, vBd, vAa, vAb, vAc, vAd);
      CTX_STEP(t0 + 1, vAa, vAb, vAc, vAd, vBa, vBb, vBc, vBd);
    }
#undef CTX_STEP
#undef CTX_CONV
#undef CTX_LOAD
  }
}

// ---------------- K10: out[m][n] = sum_k ctx[m][k]*Wv[n][k] + bv[n]/32 ----------------
// 256x128 tile, 512 threads (8 waves 4x2), 3-buf counted vmcnt(3).
// Grid 512 = 64 M-tiles x 8 N-tiles, XCD-grouped. M=16384, N=1024, K=1024.
__global__ __launch_bounds__(512, 2) void k_gemm_out(
    const unsigned short* __restrict__ A, const unsigned short* __restrict__ Bm,
    const float* __restrict__ bv, float* __restrict__ Out) {
  // per buf (24 KB): A @0 (16K: 256 rows x 64B), B @16384 (8K: 128 rows)
  __shared__ __attribute__((aligned(16))) char lds[73728];
  int tid = threadIdx.x, l = tid & 63, w = tid >> 6;   // 8 waves
  int wm = w >> 1, wn = w & 1;                          // 4 x 2
  int rid = blockIdx.x;
  int xcd = rid & 7, lid = rid >> 3;
  int bm = (xcd * 8 + (lid >> 3)) * 256;
  int bn = (lid & 7) * 128;
  int lr = l & 15, lk8 = l >> 4;
  int sF = (lr >> 1) & 3;
  int srow = tid >> 2;                      // 0..127
  int swz = (tid & 3) ^ ((tid >> 3) & 3);
  const unsigned short* a0 = A + (size_t)(bm + srow) * 1024 + swz * 8;
  const unsigned short* a1 = A + (size_t)(bm + 128 + srow) * 1024 + swz * 8;
  const unsigned short* b0 = Bm + (size_t)(bn + srow) * 1024 + swz * 8;
  char* cur = &lds[0];
  char* nxt = &lds[24576];
  char* nx2 = &lds[49152];
  f32x4 acc[4][4] = {};

#define OUT_STAGE(KN, BUF) { \
    gload_lds16(a0 + (KN), (BUF) + w * 1024); \
    gload_lds16(a1 + (KN), (BUF) + 8192 + w * 1024); \
    gload_lds16(b0 + (KN), (BUF) + 16384 + w * 1024); }

#define OUT_STEP(T) { \
    int kn = (((T) + 2 < 32) ? (T) + 2 : 31) * 32; \
    OUT_STAGE(kn, nx2); \
    SFENCE(); \
    s16x8 af[4], bf[4]; \
    _Pragma("unroll") \
    for (int i = 0; i < 4; i++) { \
      int byte = (wm * 64 + i * 16 + lr) * 64 + ((lk8 ^ sF) << 4); \
      af[i] = *(const s16x8*)(cur + byte); \
    } \
    _Pragma("unroll") \
    for (int i = 0; i < 4; i++) { \
      int byte = 16384 + (wn * 64 + i * 16 + lr) * 64 + ((lk8 ^ sF) << 4); \
      bf[i] = *(const s16x8*)(cur + byte); \
    } \
    __builtin_amdgcn_s_setprio(1); \
    _Pragma("unroll") \
    for (int i = 0; i < 4; i++) \
      _Pragma("unroll") \
      for (int j = 0; j < 4; j++) \
        acc[i][j] = __builtin_amdgcn_mfma_f32_16x16x32_bf16(af[i], bf[j], acc[i][j], 0, 0, 0); \
    __builtin_amdgcn_s_setprio(0); \
    VMCNT(3); \
    SBAR(); \
    SFENCE(); \
    { char* t_ = cur; cur = nxt; nxt = nx2; nx2 = t_; } }

  OUT_STAGE(0, cur);
  SFENCE();
  OUT_STAGE(32, nxt);
  SFENCE();
  VMCNT(3);
  SBAR();
  SFENCE();

#pragma unroll 1
  for (int t = 0; t < 32; ++t) {
    OUT_STEP(t);
  }

  int rh = (l >> 4) * 4;
#pragma unroll
  for (int i = 0; i < 4; i++)
#pragma unroll
    for (int q = 0; q < 4; q++) {
      int gm = bm + wm * 64 + i * 16 + rh + q;
#pragma unroll
      for (int j = 0; j < 4; j++) {
        int gn = bn + wn * 64 + j * 16 + lr;
        Out[(size_t)gm * 1024 + gn] = acc[i][j][q] + 0.03125f * bv[gn];
      }
    }
#undef OUT_STEP
#undef OUT_STAGE
}

extern "C" void kernel_launch(void* const* d_in, const int* in_sizes, int n_in,
                              void* d_out, int out_size, void* d_ws, size_t ws_size,
                              hipStream_t stream) {
  const float* cap = (const float*)d_in[0];
  const float* img = (const float*)d_in[1];
  const float* Wq  = (const float*)d_in[2];
  const float* bq  = (const float*)d_in[3];
  const float* Wk  = (const float*)d_in[4];
  // d_in[5] = bk: constant across r -> cancels in softmax. Unused.
  const float* Wv  = (const float*)d_in[6];
  const float* bv  = (const float*)d_in[7];
  float* out = (float*)d_out;

  char* ws = (char*)d_ws;
  if (ws_size < 40370176ull) return;  // fail loudly (output stays poisoned)
  unsigned short* ctx = (unsigned short*)(ws);               // 32 MB
  float*          Qp  = (float*)(ws + 33554432);             //  2 MB (4 K-partials)
  float*          QWp = (float*)(ws + 35651584);             //  2 MB (4 K-partials)
  unsigned short* QWh = (unsigned short*)(ws + 37748736);    // 256 KB
  unsigned short* QWl = (unsigned short*)(ws + 38010880);    // 256 KB
  unsigned short* Wvh = (unsigned short*)(ws + 38273024);    //   2 MB

  // Q partials = cap @ Wq^T  (f32 TN, K-split 4, 512 blocks x 8 steps)
  k_q_part<<<dim3(4, 32, 4), 256, 0, stream>>>(cap, Wq, Qp);
  // QW partials = (sum Qp + bq) @ Wk  (f32 NN, K-split 4)
  k_qw_part<<<dim3(4, 32, 4), 256, 0, stream>>>(Qp, bq, Wk, QWp);
  // QWh/QWl = split(sum QWp); Wvh = bf16(Wv)  (one launch)
  k_reduce_convert<<<1152, 256, 0, stream>>>(QWp, Wv, QWh, QWl, Wvh);
  // fused: scores (3-pass split bf16, bf16-staged B) + softmax/32 + ctx
  k_fused<<<256, 512, 0, stream>>>(QWh, QWl, img, ctx);
  // out = ctx @ Wv^T + bv/32  (256x128 counted-vmcnt pipeline)
  k_gemm_out<<<512, 512, 0, stream>>>(ctx, Wvh, bv, out);
}